// Round 6
// baseline (417.980 us; speedup 1.0000x reference)
//
#include <hip/hip_runtime.h>
#include <hip/hip_bf16.h>
#include <math.h>

typedef __bf16 bf16;
typedef __bf16 bf16x8 __attribute__((ext_vector_type(8)));
typedef float floatx4 __attribute__((ext_vector_type(4)));

#define GAS __attribute__((address_space(1)))
#define LAS __attribute__((address_space(3)))

static constexpr int B_ = 16, L_ = 4096, C_ = 512;
static constexpr int M_ = B_ * L_;   // 65536 rows (b,l)
static constexpr int K_ = 3 * C_;    // 1536

// ---- K1: prep_w. Round-5 post-mortem: the x f32->bf16 cast pass was stuck at
// ~1.7 TB/s effective regardless of grid shape (116 us, 29% of total) -- so the
// pass is DELETED: gemm now reg-stages A from f32 x and write-throughs xb.
// This kernel only repacks w_down (blocks 0..511, grid-stride) and does the
// boundary-row fixup (blocks 512..575).
__global__ void prep_w(const float* __restrict__ x,
                       const float* __restrict__ wd, bf16* __restrict__ wr,
                       const float* __restrict__ wp, const float* __restrict__ bp,
                       bf16* __restrict__ xp, float* __restrict__ sums) {
    __shared__ float xrow[C_];
    if (blockIdx.x < 512) {
        for (int u = blockIdx.x; u < 3072; u += 512) {
            int idx = u * 256 + threadIdx.x;   // 512*1536 total
            int o   = idx / K_;
            int rem = idx - o * K_;
            int kk  = rem >> 9;
            int i   = rem & 511;
            wr[idx] = (bf16)wd[o * K_ + i * 3 + kk];
        }
    } else {
        // fixup: rows l in [4092,4096): xp = w_pad . x + b_pad, plus their stats
        const int bid = blockIdx.x - 512;
        const int b = bid >> 2;
        const int j = bid & 3;
        for (int i = threadIdx.x; i < C_; i += 256)
            xrow[i] = x[(size_t)(b * L_ + j) * C_ + i];
        __syncthreads();
        for (int c = threadIdx.x; c < C_; c += 256) {
            const float* w = wp + (size_t)c * C_;
            float acc = 0.f;
#pragma unroll 4
            for (int i = 0; i < C_; i += 4) {
                floatx4 wv = *(const floatx4*)(w + i);
#pragma unroll
                for (int u = 0; u < 4; ++u) acc += wv[u] * xrow[i + u];
            }
            const float v = acc + bp[c];
            xp[(size_t)(b * L_ + 4092 + j) * C_ + c] = (bf16)v;
            atomicAdd(&sums[c], v);
            atomicAdd(&sums[C_ + c], v * v);
        }
    }
}

// ---- K2: dilated-conv-as-GEMM, 256x256 tile, BK=64, double-buffered LDS,
// ds_reads pipelined one phase ahead, counted vmcnt, setprio, XOR swizzle.
// NEW this round: A-operand reg-staged from f32 x (T14 issue-early/write-late:
// 8 dwordx4 loads at ph1, vmcnt-wait + cvt + ds_write_b128 at ph3 -- two MFMA
// phases cover HBM latency), and the bf16 cast is WRITTEN THROUGH to xb when
// (nb==0 && tap==0), which covers every (row,channel) exactly once. This
// deletes the 116-us prep cast pass. B staging stays global_load_lds DMA.
// vmcnt ledger (oldest-first, m135): steady ph3 outstanding =
// [B(t+1) 4][stores][A(t+2) 8][B(t+2) 4] -> vmcnt(4) retires all needed.
// WAR: ph3 ds_writes of A(t+2) land after ph2-start lgkm0 + ph2-end barrier
// retired all A(t) readers. Numerics identical to prior rounds.
__global__ __launch_bounds__(512, 2) void gemm_conv(
    const float* __restrict__ xf, const bf16* __restrict__ wr,
    const float* __restrict__ bd, bf16* __restrict__ xp,
    bf16* __restrict__ xb, float* __restrict__ sums)
{
    __shared__ bf16 As[2 * 256 * 64];   // 64 KB (2 K-tile buffers, 2 halves each)
    __shared__ bf16 Bs[2 * 256 * 64];   // 64 KB

    const int tid = threadIdx.x;        // 0..511
    const int u   = blockIdx.x;           // 0..511; XCD swizzle pairs n-blocks
    const int mb  = (u & 7) + 8 * (u >> 4);
    const int nb  = (u >> 3) & 1;
    const int m0  = mb * 256;
    const int n0  = nb * 256;

    const int wave = tid >> 6;            // 0..7
    const int lane = tid & 63;
    const int wm = wave & 1;              // 64-row subblock within each 128-half
    const int wn = wave >> 1;             // 32-col subblock within each 128-half
    const int tm = lane & 15;
    const int quad = lane >> 4;

    floatx4 acc[2][4][2][2];
#pragma unroll
    for (int a = 0; a < 2; ++a)
#pragma unroll
        for (int b = 0; b < 4; ++b)
#pragma unroll
            for (int c = 0; c < 2; ++c)
#pragma unroll
                for (int d = 0; d < 2; ++d) acc[a][b][c][d] = floatx4{0.f, 0.f, 0.f, 0.f};

    // staging map: half-tile = 128 rows x 64 cols = 1024 chunks of 16B (bf16).
    const int r0  = tid >> 3;                       // 0..63  (second row = r0+64)
    const int c0s = (tid & 7) ^ (r0 & 7);           // XOR source-chunk swizzle

    // A: issue 8 f32 dwordx4 loads for tile ts (both halves) into va
    auto issueA = [&](int ts, floatx4 (&va)[8]) {
        if (ts >= 24) return;
        const int kk = ts >> 3, i0 = (ts & 7) << 6;
#pragma unroll
        for (int eta = 0; eta < 2; ++eta) {
            int sr0 = m0 + eta * 128 + r0 + 2 * kk;      if (sr0 > M_ - 1) sr0 = M_ - 1;
            int sr1 = m0 + eta * 128 + r0 + 64 + 2 * kk; if (sr1 > M_ - 1) sr1 = M_ - 1;
            const float* p0 = xf + (size_t)sr0 * C_ + i0 + c0s * 8;
            const float* p1 = xf + (size_t)sr1 * C_ + i0 + c0s * 8;
            va[eta * 4 + 0] = *(const floatx4*)(p0);
            va[eta * 4 + 1] = *(const floatx4*)(p0 + 4);
            va[eta * 4 + 2] = *(const floatx4*)(p1);
            va[eta * 4 + 3] = *(const floatx4*)(p1 + 4);
        }
    };
    // A: cvt + ds_write (4x b128); write-through to xb for nb==0 tap-0 tiles
    auto writeA = [&](int ts, const floatx4 (&va)[8]) {
        if (ts >= 24) return;
#pragma unroll
        for (int eta = 0; eta < 2; ++eta) {
            bf16* dst = As + (ts & 1) * 16384 + eta * 8192 + tid * 8;
            bf16x8 v0, v1;
#pragma unroll
            for (int j = 0; j < 4; ++j) {
                v0[j] = (bf16)va[eta * 4 + 0][j]; v0[4 + j] = (bf16)va[eta * 4 + 1][j];
                v1[j] = (bf16)va[eta * 4 + 2][j]; v1[4 + j] = (bf16)va[eta * 4 + 3][j];
            }
            *(bf16x8*)dst = v0;
            *(bf16x8*)(dst + 4096) = v1;
            if (nb == 0 && ts < 8) {               // tap 0: each (row,ch) once
                const int i0 = ts << 6;
                const int sr0 = m0 + eta * 128 + r0;
                *(bf16x8*)(xb + (size_t)sr0 * C_ + i0 + c0s * 8) = v0;
                *(bf16x8*)(xb + (size_t)(sr0 + 64) * C_ + i0 + c0s * 8) = v1;
            }
        }
    };
    auto stageB = [&](int t, int eta) {             // 2 global_load_lds
        if (t >= 24) return;
        const int kk = t >> 3, i0 = (t & 7) << 6;
        bf16* dst = Bs + (t & 1) * 16384 + eta * 8192 + tid * 8;
        const bf16* s0 = wr + (size_t)(n0 + eta * 128 + r0) * K_ + kk * C_ + i0 + c0s * 8;
        __builtin_amdgcn_global_load_lds((const GAS void*)s0, (LAS void*)dst, 16, 0, 0);
        __builtin_amdgcn_global_load_lds((const GAS void*)(s0 + (size_t)64 * K_),
                                         (LAS void*)(dst + 4096), 16, 0, 0);
    };

    // read-side swizzled chunk offsets (elems), k-half 0/1
    const int xo0 = (quad ^ (tm & 7)) << 3;
    const int xo1 = ((4 + quad) ^ (tm & 7)) << 3;

    bf16x8 af[4][2];        // A fragments, current half: [mi][kh]
    bf16x8 bfr[2][2][2];    // B fragments, both halves: [nh][ni][kh]

    // prologue: A(0),A(1) reg-loads (16), B(0),B(1) DMA (8 instr).
    // vmcnt(8): A loads done (B may fly). writeA both (+ds_writes, +xb stores).
    // vmcnt(12): B(0) done (leaves B(1) 4 + stores 8). lgkm0 + barrier. R0(0).
    {
        floatx4 va0[8], va1[8];
        issueA(0, va0);
        issueA(1, va1);
        stageB(0, 0); stageB(0, 1); stageB(1, 0); stageB(1, 1);
        asm volatile("s_waitcnt vmcnt(8)" ::: "memory");
        writeA(0, va0);
        writeA(1, va1);
        asm volatile("s_waitcnt vmcnt(12) lgkmcnt(0)" ::: "memory");
        asm volatile("s_barrier" ::: "memory");
    }
#pragma unroll
    for (int mi = 0; mi < 4; ++mi) {
        const bf16* p = As + (wm * 64 + mi * 16 + tm) * 64;
        af[mi][0] = *(const bf16x8*)(p + xo0);
        af[mi][1] = *(const bf16x8*)(p + xo1);
    }
#pragma unroll
    for (int ni = 0; ni < 2; ++ni) {
        const bf16* p = Bs + (wn * 32 + ni * 16 + tm) * 64;
        bfr[0][ni][0] = *(const bf16x8*)(p + xo0);
        bfr[0][ni][1] = *(const bf16x8*)(p + xo1);
    }

#pragma unroll 2
    for (int t = 0; t < 24; ++t) {
        const bf16* Ab  = As + (t & 1) * 16384;
        const bf16* Bb  = Bs + (t & 1) * 16384;
        const bf16* AbN = As + ((t + 1) & 1) * 16384;
        const bf16* BbN = Bs + ((t + 1) & 1) * 16384;
        floatx4 va[8];                       // A(t+2) staging regs (ph1 -> ph3)

        // ---- ph0: wait R0; MFMA Q(0,0); issue R1 (bfr1 <- B.h1)
        asm volatile("s_waitcnt lgkmcnt(0)" ::: "memory");
        __builtin_amdgcn_sched_barrier(0);
        __builtin_amdgcn_s_setprio(1);
#pragma unroll
        for (int kh = 0; kh < 2; ++kh)
#pragma unroll
            for (int mi = 0; mi < 4; ++mi)
#pragma unroll
                for (int ni = 0; ni < 2; ++ni)
                    acc[0][mi][0][ni] = __builtin_amdgcn_mfma_f32_16x16x32_bf16(
                        af[mi][kh], bfr[0][ni][kh], acc[0][mi][0][ni], 0, 0, 0);
        __builtin_amdgcn_s_setprio(0);
#pragma unroll
        for (int ni = 0; ni < 2; ++ni) {
            const bf16* p = Bb + (128 + wn * 32 + ni * 16 + tm) * 64;
            bfr[1][ni][0] = *(const bf16x8*)(p + xo0);
            bfr[1][ni][1] = *(const bf16x8*)(p + xo1);
        }
        asm volatile("s_barrier" ::: "memory");

        // ---- ph1: wait R1; MFMA Q(0,1); issue R2 (af <- A.h1, overwrite);
        //           issue A(t+2) reg-loads; stage (t+2).B.h0 DMA
        asm volatile("s_waitcnt lgkmcnt(0)" ::: "memory");
        __builtin_amdgcn_sched_barrier(0);
        __builtin_amdgcn_s_setprio(1);
#pragma unroll
        for (int kh = 0; kh < 2; ++kh)
#pragma unroll
            for (int mi = 0; mi < 4; ++mi)
#pragma unroll
                for (int ni = 0; ni < 2; ++ni)
                    acc[0][mi][1][ni] = __builtin_amdgcn_mfma_f32_16x16x32_bf16(
                        af[mi][kh], bfr[1][ni][kh], acc[0][mi][1][ni], 0, 0, 0);
        __builtin_amdgcn_s_setprio(0);
#pragma unroll
        for (int mi = 0; mi < 4; ++mi) {
            const bf16* p = Ab + (128 + wm * 64 + mi * 16 + tm) * 64;
            af[mi][0] = *(const bf16x8*)(p + xo0);
            af[mi][1] = *(const bf16x8*)(p + xo1);
        }
        issueA(t + 2, va);
        stageB(t + 2, 0);
        asm volatile("s_barrier" ::: "memory");

        // ---- ph2: wait R2; MFMA Q(1,1); stage (t+2).B.h1 DMA
        asm volatile("s_waitcnt lgkmcnt(0)" ::: "memory");
        __builtin_amdgcn_sched_barrier(0);
        __builtin_amdgcn_s_setprio(1);
#pragma unroll
        for (int kh = 0; kh < 2; ++kh)
#pragma unroll
            for (int mi = 0; mi < 4; ++mi)
#pragma unroll
                for (int ni = 0; ni < 2; ++ni)
                    acc[1][mi][1][ni] = __builtin_amdgcn_mfma_f32_16x16x32_bf16(
                        af[mi][kh], bfr[1][ni][kh], acc[1][mi][1][ni], 0, 0, 0);
        __builtin_amdgcn_s_setprio(0);
        stageB(t + 2, 1);
        asm volatile("s_barrier" ::: "memory");

        // ---- ph3: counted vmcnt (A(t+2) loads + B(t+1) DMA landed; B(t+2)
        //           still in flight); writeA(t+2) (+xb stores); barrier;
        //           MFMA Q(1,0) (register-only); issue R0(t+1)
        if (t < 22)       { asm volatile("s_waitcnt vmcnt(4)" ::: "memory"); }
        else if (t == 22) { asm volatile("s_waitcnt vmcnt(0)" ::: "memory"); }
        writeA(t + 2, va);
        asm volatile("s_barrier" ::: "memory");
        __builtin_amdgcn_s_setprio(1);
#pragma unroll
        for (int kh = 0; kh < 2; ++kh)
#pragma unroll
            for (int mi = 0; mi < 4; ++mi)
#pragma unroll
                for (int ni = 0; ni < 2; ++ni)
                    acc[1][mi][0][ni] = __builtin_amdgcn_mfma_f32_16x16x32_bf16(
                        af[mi][kh], bfr[0][ni][kh], acc[1][mi][0][ni], 0, 0, 0);
        __builtin_amdgcn_s_setprio(0);
        if (t < 23) {
#pragma unroll
            for (int mi = 0; mi < 4; ++mi) {
                const bf16* p = AbN + (wm * 64 + mi * 16 + tm) * 64;
                af[mi][0] = *(const bf16x8*)(p + xo0);
                af[mi][1] = *(const bf16x8*)(p + xo1);
            }
#pragma unroll
            for (int ni = 0; ni < 2; ++ni) {
                const bf16* p = BbN + (wn * 32 + ni * 16 + tm) * 64;
                bfr[0][ni][0] = *(const bf16x8*)(p + xo0);
                bfr[0][ni][1] = *(const bf16x8*)(p + xo1);
            }
        }
        asm volatile("s_barrier" ::: "memory");
    }

    // epilogue: + bias, store bf16 (valid rows only; boundary rows owned by the
    // fixup branch of prep_w), fused stats. C/D: col=lane&15, row=quad*4+reg.
    float bias[2][2], s[2][2], q[2][2];
#pragma unroll
    for (int nh = 0; nh < 2; ++nh)
#pragma unroll
        for (int ni = 0; ni < 2; ++ni) {
            bias[nh][ni] = bd[n0 + nh * 128 + wn * 32 + ni * 16 + tm];
            s[nh][ni] = 0.f; q[nh][ni] = 0.f;
        }

#pragma unroll
    for (int mh = 0; mh < 2; ++mh)
#pragma unroll
        for (int mi = 0; mi < 4; ++mi)
#pragma unroll
            for (int r = 0; r < 4; ++r) {
                const int m = m0 + mh * 128 + wm * 64 + mi * 16 + quad * 4 + r;
                const bool valid = (m & (L_ - 1)) < L_ - 4;
                bf16* dst = xp + (size_t)m * C_ + n0 + wn * 32 + tm;
#pragma unroll
                for (int nh = 0; nh < 2; ++nh)
#pragma unroll
                    for (int ni = 0; ni < 2; ++ni) {
                        const float v = acc[mh][mi][nh][ni][r] + bias[nh][ni];
                        if (valid) {
                            dst[nh * 128 + ni * 16] = (bf16)v;
                            s[nh][ni] += v; q[nh][ni] += v * v;
                        }
                    }
            }
#pragma unroll
    for (int nh = 0; nh < 2; ++nh)
#pragma unroll
        for (int ni = 0; ni < 2; ++ni) {
            float sv = s[nh][ni], qv = q[nh][ni];
            sv += __shfl_xor(sv, 16); sv += __shfl_xor(sv, 32);
            qv += __shfl_xor(qv, 16); qv += __shfl_xor(qv, 32);
            if (quad == 0) {
                const int c = n0 + nh * 128 + wn * 32 + ni * 16 + tm;
                atomicAdd(&sums[c], sv);
                atomicAdd(&sums[C_ + c], qv);
            }
        }
}

// ---- K4: BN(from raw sums) -> ELU -> +residual(bf16) -> maxpool(3,2,pad1) ->
// [B,L/2,C] f32. 2048 blocks; each thread keeps fixed (channel-group, t) so BN
// coefficients hoist; strides over b.
__global__ void final_pool(const bf16* __restrict__ xp, const bf16* __restrict__ xb,
                           const float* __restrict__ sums, const float* __restrict__ gamma,
                           const float* __restrict__ beta, float* __restrict__ out)
{
    const int gid0 = blockIdx.x * 256 + threadIdx.x;  // 524288 ids; total 2097152
    const int cg = gid0 & 63;
    const int t  = (gid0 >> 6) & 2047;
    const int b0 = gid0 >> 17;                        // 0..3
    const int c0 = cg << 3;

    float sc[8], sh[8];
    const float invn = 1.0f / 65536.0f;
#pragma unroll
    for (int j = 0; j < 8; ++j) {
        const int c = c0 + j;
        float mean = sums[c] * invn;
        float var  = sums[C_ + c] * invn - mean * mean;
        float scale = gamma[c] * rsqrtf(var + 1e-5f);
        sc[j] = scale;
        sh[j] = beta[c] - mean * scale;
    }

    for (int b = b0; b < B_; b += 4) {
        float best[8];
#pragma unroll
        for (int j = 0; j < 8; ++j) best[j] = -INFINITY;

#pragma unroll
        for (int dl = -1; dl <= 1; ++dl) {
            const int l = 2 * t + dl;
            if (l < 0) continue;                        // right edge never exceeds 4095
            const size_t off = (size_t)(b * L_ + l) * C_ + c0;
            bf16x8 xpv = *(const bf16x8*)(xp + off);
            bf16x8 xv  = *(const bf16x8*)(xb + off);
#pragma unroll
            for (int j = 0; j < 8; ++j) {
                float z = sc[j] * (float)xpv[j] + sh[j];
                float y = (z > 0.f) ? z : (__expf(z) - 1.f);
                y += (float)xv[j];
                best[j] = fmaxf(best[j], y);
            }
        }
        floatx4 o0, o1;
#pragma unroll
        for (int j = 0; j < 4; ++j) { o0[j] = best[j]; o1[j] = best[4 + j]; }
        const size_t og = ((size_t)b << 17) | ((size_t)t << 6) | cg;
        *(floatx4*)(out + og * 8) = o0;
        *(floatx4*)(out + og * 8 + 4) = o1;
    }
}

extern "C" void kernel_launch(void* const* d_in, const int* in_sizes, int n_in,
                              void* d_out, int out_size, void* d_ws, size_t ws_size,
                              hipStream_t stream)
{
    const float* x      = (const float*)d_in[0];
    const float* w_down = (const float*)d_in[1];
    const float* b_down = (const float*)d_in[2];
    const float* w_pad  = (const float*)d_in[3];
    const float* b_pad  = (const float*)d_in[4];
    const float* gamma  = (const float*)d_in[5];
    const float* beta   = (const float*)d_in[6];
    float* out = (float*)d_out;

    char* ws = (char*)d_ws;
    bf16*  xb   = (bf16*)ws;                                        // 64 MiB  [B*L][C] bf16 x (written by gemm)
    bf16*  xp   = (bf16*)(ws + (size_t)M_ * C_ * 2);                // 64 MiB  [B*L][C]
    bf16*  wr   = (bf16*)(ws + (size_t)M_ * C_ * 4);                // 1.5 MiB [O][K]
    float* sums = (float*)(ws + (size_t)M_ * C_ * 4 + (size_t)C_ * K_ * 2);  // 1024 f32

    hipMemsetAsync(sums, 0, 2 * C_ * sizeof(float), stream);
    prep_w<<<dim3(512 + 64), dim3(256), 0, stream>>>(x, w_down, wr,
                                                     w_pad, b_pad, xp, sums);
    gemm_conv<<<dim3(512), dim3(512), 0, stream>>>(x, wr, b_down, xp, xb, sums);
    final_pool<<<dim3(2048), dim3(256), 0, stream>>>(xp, xb, sums, gamma, beta, out);
}

// Round 7
// 408.651 us; speedup vs baseline: 1.0228x; 1.0228x over previous
//
#include <hip/hip_runtime.h>
#include <hip/hip_bf16.h>
#include <math.h>

typedef __bf16 bf16;
typedef __bf16 bf16x8 __attribute__((ext_vector_type(8)));
typedef float floatx4 __attribute__((ext_vector_type(4)));

#define GAS __attribute__((address_space(1)))
#define LAS __attribute__((address_space(3)))

static constexpr int B_ = 16, L_ = 4096, C_ = 512;
static constexpr int M_ = B_ * L_;   // 65536 rows (b,l)
static constexpr int K_ = 3 * C_;    // 1536

// ---- K1: prep_w: repack w_down (blocks 0..511) + boundary-row fixup (512..575).
__global__ void prep_w(const float* __restrict__ x,
                       const float* __restrict__ wd, bf16* __restrict__ wr,
                       const float* __restrict__ wp, const float* __restrict__ bp,
                       bf16* __restrict__ xp, float* __restrict__ sums) {
    __shared__ float xrow[C_];
    if (blockIdx.x < 512) {
        for (int u = blockIdx.x; u < 3072; u += 512) {
            int idx = u * 256 + threadIdx.x;   // 512*1536 total
            int o   = idx / K_;
            int rem = idx - o * K_;
            int kk  = rem >> 9;
            int i   = rem & 511;
            wr[idx] = (bf16)wd[o * K_ + i * 3 + kk];
        }
    } else {
        // fixup: rows l in [4092,4096): xp = w_pad . x + b_pad, plus their stats
        const int bid = blockIdx.x - 512;
        const int b = bid >> 2;
        const int j = bid & 3;
        for (int i = threadIdx.x; i < C_; i += 256)
            xrow[i] = x[(size_t)(b * L_ + j) * C_ + i];
        __syncthreads();
        for (int c = threadIdx.x; c < C_; c += 256) {
            const float* w = wp + (size_t)c * C_;
            float acc = 0.f;
#pragma unroll 4
            for (int i = 0; i < C_; i += 4) {
                floatx4 wv = *(const floatx4*)(w + i);
#pragma unroll
                for (int u = 0; u < 4; ++u) acc += wv[u] * xrow[i + u];
            }
            const float v = acc + bp[c];
            xp[(size_t)(b * L_ + 4092 + j) * C_ + c] = (bf16)v;
            atomicAdd(&sums[c], v);
            atomicAdd(&sums[C_ + c], v * v);
        }
    }
}

// ---- K2: dilated-conv-as-GEMM, 256x256 tile, BK=64, double-buffered LDS,
// ds_reads pipelined one phase ahead, counted vmcnt, setprio, XOR swizzle.
// A-operand reg-staged from f32 x (issue ph1, vmcnt-wait + cvt + ds_write ph3).
// Round-6 post-mortem: kernel is pure-BW-bound (349 MB @ 1.95 TB/s = 184 us
// exactly). The 67 MB xb write-through inflated WRITE_SIZE and sat in the
// vmcnt retirement queue at ph3 -> DELETED this round (final_pool takes the
// residual from f32 x, which is L3-resident after this kernel streams it).
// vmcnt ledger (no stores): steady ph3 queue =
// [B(t+1) 4][A(t+2) 8][B(t+2) 4] -> vmcnt(4) retires A(t+2)+B(t+1).
// Prologue queue [A0 8][A1 8][B0 4][B1 4]: vmcnt(8) -> A landed; after writeA
// (LDS-only) vmcnt(4) -> B0 landed.
__global__ __launch_bounds__(512, 2) void gemm_conv(
    const float* __restrict__ xf, const bf16* __restrict__ wr,
    const float* __restrict__ bd, bf16* __restrict__ xp, float* __restrict__ sums)
{
    __shared__ bf16 As[2 * 256 * 64];   // 64 KB (2 K-tile buffers, 2 halves each)
    __shared__ bf16 Bs[2 * 256 * 64];   // 64 KB

    const int tid = threadIdx.x;        // 0..511
    const int u   = blockIdx.x;           // 0..511; XCD swizzle pairs n-blocks
    const int mb  = (u & 7) + 8 * (u >> 4);
    const int nb  = (u >> 3) & 1;
    const int m0  = mb * 256;
    const int n0  = nb * 256;

    const int wave = tid >> 6;            // 0..7
    const int lane = tid & 63;
    const int wm = wave & 1;              // 64-row subblock within each 128-half
    const int wn = wave >> 1;             // 32-col subblock within each 128-half
    const int tm = lane & 15;
    const int quad = lane >> 4;

    floatx4 acc[2][4][2][2];
#pragma unroll
    for (int a = 0; a < 2; ++a)
#pragma unroll
        for (int b = 0; b < 4; ++b)
#pragma unroll
            for (int c = 0; c < 2; ++c)
#pragma unroll
                for (int d = 0; d < 2; ++d) acc[a][b][c][d] = floatx4{0.f, 0.f, 0.f, 0.f};

    // staging map: half-tile = 128 rows x 64 cols = 1024 chunks of 16B (bf16).
    const int r0  = tid >> 3;                       // 0..63  (second row = r0+64)
    const int c0s = (tid & 7) ^ (r0 & 7);           // XOR source-chunk swizzle

    // A: issue 8 f32 dwordx4 loads for tile ts (both halves) into va
    auto issueA = [&](int ts, floatx4 (&va)[8]) {
        if (ts >= 24) return;
        const int kk = ts >> 3, i0 = (ts & 7) << 6;
#pragma unroll
        for (int eta = 0; eta < 2; ++eta) {
            int sr0 = m0 + eta * 128 + r0 + 2 * kk;      if (sr0 > M_ - 1) sr0 = M_ - 1;
            int sr1 = m0 + eta * 128 + r0 + 64 + 2 * kk; if (sr1 > M_ - 1) sr1 = M_ - 1;
            const float* p0 = xf + (size_t)sr0 * C_ + i0 + c0s * 8;
            const float* p1 = xf + (size_t)sr1 * C_ + i0 + c0s * 8;
            va[eta * 4 + 0] = *(const floatx4*)(p0);
            va[eta * 4 + 1] = *(const floatx4*)(p0 + 4);
            va[eta * 4 + 2] = *(const floatx4*)(p1);
            va[eta * 4 + 3] = *(const floatx4*)(p1 + 4);
        }
    };
    // A: cvt + ds_write (4x b128) -- LDS only, no global stores
    auto writeA = [&](int ts, const floatx4 (&va)[8]) {
        if (ts >= 24) return;
#pragma unroll
        for (int eta = 0; eta < 2; ++eta) {
            bf16* dst = As + (ts & 1) * 16384 + eta * 8192 + tid * 8;
            bf16x8 v0, v1;
#pragma unroll
            for (int j = 0; j < 4; ++j) {
                v0[j] = (bf16)va[eta * 4 + 0][j]; v0[4 + j] = (bf16)va[eta * 4 + 1][j];
                v1[j] = (bf16)va[eta * 4 + 2][j]; v1[4 + j] = (bf16)va[eta * 4 + 3][j];
            }
            *(bf16x8*)dst = v0;
            *(bf16x8*)(dst + 4096) = v1;
        }
    };
    auto stageB = [&](int t, int eta) {             // 2 global_load_lds
        if (t >= 24) return;
        const int kk = t >> 3, i0 = (t & 7) << 6;
        bf16* dst = Bs + (t & 1) * 16384 + eta * 8192 + tid * 8;
        const bf16* s0 = wr + (size_t)(n0 + eta * 128 + r0) * K_ + kk * C_ + i0 + c0s * 8;
        __builtin_amdgcn_global_load_lds((const GAS void*)s0, (LAS void*)dst, 16, 0, 0);
        __builtin_amdgcn_global_load_lds((const GAS void*)(s0 + (size_t)64 * K_),
                                         (LAS void*)(dst + 4096), 16, 0, 0);
    };

    // read-side swizzled chunk offsets (elems), k-half 0/1
    const int xo0 = (quad ^ (tm & 7)) << 3;
    const int xo1 = ((4 + quad) ^ (tm & 7)) << 3;

    bf16x8 af[4][2];        // A fragments, current half: [mi][kh]
    bf16x8 bfr[2][2][2];    // B fragments, both halves: [nh][ni][kh]

    // prologue
    {
        floatx4 va0[8], va1[8];
        issueA(0, va0);
        issueA(1, va1);
        stageB(0, 0); stageB(0, 1); stageB(1, 0); stageB(1, 1);
        asm volatile("s_waitcnt vmcnt(8)" ::: "memory");   // A(0),A(1) landed
        writeA(0, va0);
        writeA(1, va1);
        asm volatile("s_waitcnt vmcnt(4) lgkmcnt(0)" ::: "memory"); // B(0) landed
        asm volatile("s_barrier" ::: "memory");
    }
#pragma unroll
    for (int mi = 0; mi < 4; ++mi) {
        const bf16* p = As + (wm * 64 + mi * 16 + tm) * 64;
        af[mi][0] = *(const bf16x8*)(p + xo0);
        af[mi][1] = *(const bf16x8*)(p + xo1);
    }
#pragma unroll
    for (int ni = 0; ni < 2; ++ni) {
        const bf16* p = Bs + (wn * 32 + ni * 16 + tm) * 64;
        bfr[0][ni][0] = *(const bf16x8*)(p + xo0);
        bfr[0][ni][1] = *(const bf16x8*)(p + xo1);
    }

#pragma unroll 2
    for (int t = 0; t < 24; ++t) {
        const bf16* Ab  = As + (t & 1) * 16384;
        const bf16* Bb  = Bs + (t & 1) * 16384;
        const bf16* AbN = As + ((t + 1) & 1) * 16384;
        const bf16* BbN = Bs + ((t + 1) & 1) * 16384;
        floatx4 va[8];                       // A(t+2) staging regs (ph1 -> ph3)

        // ---- ph0: wait R0; MFMA Q(0,0); issue R1 (bfr1 <- B.h1)
        asm volatile("s_waitcnt lgkmcnt(0)" ::: "memory");
        __builtin_amdgcn_sched_barrier(0);
        __builtin_amdgcn_s_setprio(1);
#pragma unroll
        for (int kh = 0; kh < 2; ++kh)
#pragma unroll
            for (int mi = 0; mi < 4; ++mi)
#pragma unroll
                for (int ni = 0; ni < 2; ++ni)
                    acc[0][mi][0][ni] = __builtin_amdgcn_mfma_f32_16x16x32_bf16(
                        af[mi][kh], bfr[0][ni][kh], acc[0][mi][0][ni], 0, 0, 0);
        __builtin_amdgcn_s_setprio(0);
#pragma unroll
        for (int ni = 0; ni < 2; ++ni) {
            const bf16* p = Bb + (128 + wn * 32 + ni * 16 + tm) * 64;
            bfr[1][ni][0] = *(const bf16x8*)(p + xo0);
            bfr[1][ni][1] = *(const bf16x8*)(p + xo1);
        }
        asm volatile("s_barrier" ::: "memory");

        // ---- ph1: wait R1; MFMA Q(0,1); issue R2 (af <- A.h1, overwrite);
        //           issue A(t+2) reg-loads; stage (t+2).B.h0 DMA
        asm volatile("s_waitcnt lgkmcnt(0)" ::: "memory");
        __builtin_amdgcn_sched_barrier(0);
        __builtin_amdgcn_s_setprio(1);
#pragma unroll
        for (int kh = 0; kh < 2; ++kh)
#pragma unroll
            for (int mi = 0; mi < 4; ++mi)
#pragma unroll
                for (int ni = 0; ni < 2; ++ni)
                    acc[0][mi][1][ni] = __builtin_amdgcn_mfma_f32_16x16x32_bf16(
                        af[mi][kh], bfr[1][ni][kh], acc[0][mi][1][ni], 0, 0, 0);
        __builtin_amdgcn_s_setprio(0);
#pragma unroll
        for (int mi = 0; mi < 4; ++mi) {
            const bf16* p = Ab + (128 + wm * 64 + mi * 16 + tm) * 64;
            af[mi][0] = *(const bf16x8*)(p + xo0);
            af[mi][1] = *(const bf16x8*)(p + xo1);
        }
        issueA(t + 2, va);
        stageB(t + 2, 0);
        asm volatile("s_barrier" ::: "memory");

        // ---- ph2: wait R2; MFMA Q(1,1); stage (t+2).B.h1 DMA
        asm volatile("s_waitcnt lgkmcnt(0)" ::: "memory");
        __builtin_amdgcn_sched_barrier(0);
        __builtin_amdgcn_s_setprio(1);
#pragma unroll
        for (int kh = 0; kh < 2; ++kh)
#pragma unroll
            for (int mi = 0; mi < 4; ++mi)
#pragma unroll
                for (int ni = 0; ni < 2; ++ni)
                    acc[1][mi][1][ni] = __builtin_amdgcn_mfma_f32_16x16x32_bf16(
                        af[mi][kh], bfr[1][ni][kh], acc[1][mi][1][ni], 0, 0, 0);
        __builtin_amdgcn_s_setprio(0);
        stageB(t + 2, 1);
        asm volatile("s_barrier" ::: "memory");

        // ---- ph3: counted vmcnt (A(t+2) + B(t+1) landed; B(t+2) in flight);
        //           writeA(t+2) (LDS); barrier; MFMA Q(1,0); issue R0(t+1)
        if (t < 22)       { asm volatile("s_waitcnt vmcnt(4)" ::: "memory"); }
        else if (t == 22) { asm volatile("s_waitcnt vmcnt(0)" ::: "memory"); }
        writeA(t + 2, va);
        asm volatile("s_barrier" ::: "memory");
        __builtin_amdgcn_s_setprio(1);
#pragma unroll
        for (int kh = 0; kh < 2; ++kh)
#pragma unroll
            for (int mi = 0; mi < 4; ++mi)
#pragma unroll
                for (int ni = 0; ni < 2; ++ni)
                    acc[1][mi][0][ni] = __builtin_amdgcn_mfma_f32_16x16x32_bf16(
                        af[mi][kh], bfr[0][ni][kh], acc[1][mi][0][ni], 0, 0, 0);
        __builtin_amdgcn_s_setprio(0);
        if (t < 23) {
#pragma unroll
            for (int mi = 0; mi < 4; ++mi) {
                const bf16* p = AbN + (wm * 64 + mi * 16 + tm) * 64;
                af[mi][0] = *(const bf16x8*)(p + xo0);
                af[mi][1] = *(const bf16x8*)(p + xo1);
            }
#pragma unroll
            for (int ni = 0; ni < 2; ++ni) {
                const bf16* p = BbN + (wn * 32 + ni * 16 + tm) * 64;
                bfr[0][ni][0] = *(const bf16x8*)(p + xo0);
                bfr[0][ni][1] = *(const bf16x8*)(p + xo1);
            }
        }
        asm volatile("s_barrier" ::: "memory");
    }

    // epilogue: + bias, store bf16 (valid rows only; boundary rows owned by
    // prep_w's fixup), fused stats. C/D: col=lane&15, row=quad*4+reg.
    float bias[2][2], s[2][2], q[2][2];
#pragma unroll
    for (int nh = 0; nh < 2; ++nh)
#pragma unroll
        for (int ni = 0; ni < 2; ++ni) {
            bias[nh][ni] = bd[n0 + nh * 128 + wn * 32 + ni * 16 + tm];
            s[nh][ni] = 0.f; q[nh][ni] = 0.f;
        }

#pragma unroll
    for (int mh = 0; mh < 2; ++mh)
#pragma unroll
        for (int mi = 0; mi < 4; ++mi)
#pragma unroll
            for (int r = 0; r < 4; ++r) {
                const int m = m0 + mh * 128 + wm * 64 + mi * 16 + quad * 4 + r;
                const bool valid = (m & (L_ - 1)) < L_ - 4;
                bf16* dst = xp + (size_t)m * C_ + n0 + wn * 32 + tm;
#pragma unroll
                for (int nh = 0; nh < 2; ++nh)
#pragma unroll
                    for (int ni = 0; ni < 2; ++ni) {
                        const float v = acc[mh][mi][nh][ni][r] + bias[nh][ni];
                        if (valid) {
                            dst[nh * 128 + ni * 16] = (bf16)v;
                            s[nh][ni] += v; q[nh][ni] += v * v;
                        }
                    }
            }
#pragma unroll
    for (int nh = 0; nh < 2; ++nh)
#pragma unroll
        for (int ni = 0; ni < 2; ++ni) {
            float sv = s[nh][ni], qv = q[nh][ni];
            sv += __shfl_xor(sv, 16); sv += __shfl_xor(sv, 32);
            qv += __shfl_xor(qv, 16); qv += __shfl_xor(qv, 32);
            if (quad == 0) {
                const int c = n0 + nh * 128 + wn * 32 + ni * 16 + tm;
                atomicAdd(&sums[c], sv);
                atomicAdd(&sums[C_ + c], qv);
            }
        }
}

// ---- K4: BN(from raw sums) -> ELU -> +residual(x f32) -> maxpool(3,2,pad1) ->
// [B,L/2,C] f32. Residual now read from f32 x directly (xb deleted; x is
// L3-resident after gemm streams it). Each thread computes a t-PAIR: adjacent
// pool windows share the boundary row (5 l-loads for 2 outputs instead of 6)
// and the deeper per-thread load batch raises in-flight VMEM (the knob that
// got gemm to 1.95 TB/s).
__global__ void final_pool(const bf16* __restrict__ xp, const float* __restrict__ xf,
                           const float* __restrict__ sums, const float* __restrict__ gamma,
                           const float* __restrict__ beta, float* __restrict__ out)
{
    const int gid = blockIdx.x * 256 + threadIdx.x;  // 2048*256 = 524288 ids
    const int cg = gid & 63;                         // 8-channel group
    const int tp = (gid >> 6) & 1023;                // t-pair: outputs t=2tp, 2tp+1
    const int b0 = gid >> 16;                        // 0..7
    const int c0 = cg << 3;

    float sc[8], sh[8];
    const float invn = 1.0f / 65536.0f;
#pragma unroll
    for (int j = 0; j < 8; ++j) {
        const int c = c0 + j;
        float mean = sums[c] * invn;
        float var  = sums[C_ + c] * invn - mean * mean;
        float scale = gamma[c] * rsqrtf(var + 1e-5f);
        sc[j] = scale;
        sh[j] = beta[c] - mean * scale;
    }

    for (int b = b0; b < B_; b += 8) {
        // l = 4tp-1 .. 4tp+3; y[i] = ELU(BN(xp)) + x for l = 4tp-1+i
        float y[5][8];
#pragma unroll
        for (int i = 0; i < 5; ++i) {
            const int l = 4 * tp - 1 + i;
            if (l < 0) {
#pragma unroll
                for (int j = 0; j < 8; ++j) y[i][j] = -INFINITY;
                continue;
            }
            const size_t off = (size_t)(b * L_ + l) * C_ + c0;
            bf16x8 xpv = *(const bf16x8*)(xp + off);
            floatx4 xa = *(const floatx4*)(xf + off);
            floatx4 xbv = *(const floatx4*)(xf + off + 4);
#pragma unroll
            for (int j = 0; j < 8; ++j) {
                float z = sc[j] * (float)xpv[j] + sh[j];
                float e = (z > 0.f) ? z : (__expf(z) - 1.f);
                y[i][j] = e + (j < 4 ? xa[j] : xbv[j - 4]);
            }
        }
        floatx4 o0a, o0b, o1a, o1b;
#pragma unroll
        for (int j = 0; j < 4; ++j) {
            o0a[j] = fmaxf(fmaxf(y[0][j], y[1][j]), y[2][j]);
            o0b[j] = fmaxf(fmaxf(y[0][4 + j], y[1][4 + j]), y[2][4 + j]);
            o1a[j] = fmaxf(fmaxf(y[2][j], y[3][j]), y[4][j]);
            o1b[j] = fmaxf(fmaxf(y[2][4 + j], y[3][4 + j]), y[4][4 + j]);
        }
        const size_t og0 = ((size_t)b * 2048 + 2 * tp) * C_ + c0;
        *(floatx4*)(out + og0) = o0a;
        *(floatx4*)(out + og0 + 4) = o0b;
        *(floatx4*)(out + og0 + C_) = o1a;
        *(floatx4*)(out + og0 + C_ + 4) = o1b;
    }
}

extern "C" void kernel_launch(void* const* d_in, const int* in_sizes, int n_in,
                              void* d_out, int out_size, void* d_ws, size_t ws_size,
                              hipStream_t stream)
{
    const float* x      = (const float*)d_in[0];
    const float* w_down = (const float*)d_in[1];
    const float* b_down = (const float*)d_in[2];
    const float* w_pad  = (const float*)d_in[3];
    const float* b_pad  = (const float*)d_in[4];
    const float* gamma  = (const float*)d_in[5];
    const float* beta   = (const float*)d_in[6];
    float* out = (float*)d_out;

    char* ws = (char*)d_ws;
    bf16*  xp   = (bf16*)ws;                                        // 64 MiB  [B*L][C]
    bf16*  wr   = (bf16*)(ws + (size_t)M_ * C_ * 2);                // 1.5 MiB [O][K]
    float* sums = (float*)(ws + (size_t)M_ * C_ * 2 + (size_t)C_ * K_ * 2);  // 1024 f32

    hipMemsetAsync(sums, 0, 2 * C_ * sizeof(float), stream);
    prep_w<<<dim3(512 + 64), dim3(256), 0, stream>>>(x, w_down, wr,
                                                     w_pad, b_pad, xp, sums);
    gemm_conv<<<dim3(512), dim3(512), 0, stream>>>(x, wr, b_down, xp, sums);
    final_pool<<<dim3(2048), dim3(256), 0, stream>>>(xp, x, sums, gamma, beta, out);
}